// Round 16
// baseline (537.069 us; speedup 1.0000x reference)
//
#include <hip/hip_runtime.h>
#include <hip/hip_bf16.h>

#define DEV __device__ __forceinline__

namespace {

constexpr int cB = 2, cT = 8, cH = 32, cW = 32, cC = 192;
constexpr int cDI = 384, cN = 16, cK = 4, cDTR = 12, cLT = 77, cHID = 768;
constexpr int cL  = cT * cH * cW;      // 8192
constexpr int cBL = cB * cL;           // 16384
constexpr int SEG = 128, SEGLEN = cL / SEG;   // 128 segments x 64 steps
constexpr int XROW = cDTR + 2 * cN;    // 44 live cols
constexpr int XSTR = 48;               // padded row stride (float4-aligned)

typedef __attribute__((ext_vector_type(8))) short bf16x8;
typedef __attribute__((ext_vector_type(4))) float f32x4;
typedef __attribute__((ext_vector_type(2))) float f32x2;
typedef __attribute__((ext_vector_type(4))) short short4v;

// ---------- scalar helpers ----------
DEV float bfu2f(unsigned short u) { return __uint_as_float(((unsigned)u) << 16); }
DEV float ldsel(const void* p, size_t i, int f32) {
  return f32 ? ((const float*)p)[i] : bfu2f(((const unsigned short*)p)[i]);
}
template <int F32>
DEV float4 ld4(const void* p, size_t e) {   // e: element index, multiple of 4
  if (F32) return *(const float4*)((const float*)p + e);
  ushort4 u = *(const ushort4*)((const unsigned short*)p + e);
  return make_float4(bfu2f(u.x), bfu2f(u.y), bfu2f(u.z), bfu2f(u.w));
}
DEV short f2bf(float f) {   // RNE float->bf16 bits
  unsigned u = __float_as_uint(f);
  u += 0x7fffu + ((u >> 16) & 1u);
  return (short)(u >> 16);
}
DEV float siluf(float x) { return x / (1.f + __expf(-x)); }
DEV float softplusf(float x) { return (x > 20.f) ? x : __logf(1.f + __expf(x)); }
DEV float gelut(float x) {            // tanh-approx gelu (JAX default)
  float u = 0.7978845608028654f * (x + 0.044715f * x * x * x);
  float e = __expf(2.f * u);
  float th = 1.f - 2.f / (e + 1.f);
  return 0.5f * x * (1.f + th);
}
DEV f32x2 mk2(float a, float b) { f32x2 v; v[0] = a; v[1] = b; return v; }
DEV float4 cfma(float4 acc, float4 w, float4 x) {
  acc.x += w.x * x.x; acc.y += w.y * x.y;
  acc.z += w.z * x.z; acc.w += w.w * x.w;
  return acc;
}

// ---------- dtype detector (validated: inputs are fp32) ----------
__global__ void __launch_bounds__(256) detect_kernel(
    const unsigned short* __restrict__ xa, const unsigned short* __restrict__ wp,
    int* __restrict__ flg) {
  __shared__ int cnt[2];
  if (threadIdx.x < 2) cnt[threadIdx.x] = 0;
  __syncthreads();
  int l0 = 0, l1 = 0;
  for (int i = threadIdx.x; i < 1024; i += 256) {
    float v = bfu2f(xa[2 * i]); float a = fabsf(v);
    if (v == 0.f || (a > 1e-8f && a < 1e4f)) l0++;
    float u = bfu2f(wp[2 * i]); float bq = fabsf(u);
    if (u == 0.f || (bq > 1e-8f && bq < 1e4f)) l1++;
  }
  atomicAdd(&cnt[0], l0); atomicAdd(&cnt[1], l1);
  __syncthreads();
  if (threadIdx.x == 0) {
    flg[0] = (cnt[0] < 614) ? 1 : 0;
    flg[1] = (cnt[1] < 614) ? 1 : 0;
    flg[2] = 1;
  }
}

// ---------- conv weight prep: transpose [Ch][27] -> [27][Ch] fp32, decode biases ----------
__global__ void __launch_bounds__(256) prep_kernel(
    const void* __restrict__ cvw, const void* __restrict__ cvb,
    const void* __restrict__ c1w, const void* __restrict__ c1b,
    const void* __restrict__ c2w, const void* __restrict__ c2b,
    const int* __restrict__ flg,
    float* __restrict__ wcv, float* __restrict__ bcv,
    float* __restrict__ w1, float* __restrict__ b1,
    float* __restrict__ w2, float* __restrict__ b2) {
  int pf = flg[1];
  int i = blockIdx.x * 256 + threadIdx.x;
  int r = i;
  if (r < 27 * cDI) { int j = r / cDI, d = r % cDI; wcv[r] = ldsel(cvw, (size_t)d * 27 + j, pf); return; }
  r -= 27 * cDI;
  if (r < cDI) { bcv[r] = ldsel(cvb, r, pf); return; }
  r -= cDI;
  if (r < 27 * cC) { int j = r / cC, c = r % cC; w1[r] = ldsel(c1w, (size_t)c * 27 + j, pf); return; }
  r -= 27 * cC;
  if (r < cC) { b1[r] = ldsel(c1b, r, pf); return; }
  r -= cC;
  if (r < 27 * cC) { int j = r / cC, c = r % cC; w2[r] = ldsel(c2w, (size_t)c * 27 + j, pf); return; }
  r -= 27 * cC;
  if (r < cC) { b2[r] = ldsel(c2b, r, pf); return; }
}

// ---------- CPE (depthwise 3x3x3 + residual), 2x2 (h x w) voxels/thread ----------
template <int F32>
DEV void cpe_body(const void* __restrict__ xin, const float* __restrict__ wT,
                  const float* __restrict__ bs, int idx, float* __restrict__ out) {
  int c = (idx % (cC / 4)) * 4;
  int rest = idx / (cC / 4);
  int w0 = (rest & 15) << 1; rest >>= 4;
  int h0 = (rest & 15) << 1; rest >>= 4;
  int t = rest & 7; int b = rest >> 3;
  float4 bias = *(const float4*)(bs + c);
  float4 a00 = bias, a01 = bias, a10 = bias, a11 = bias;   // [oh][ow]
  const float4 zero = make_float4(0.f, 0.f, 0.f, 0.f);
#pragma unroll
  for (int dz = 0; dz < 3; ++dz) {
    int tt = t + dz - 1; if ((unsigned)tt >= (unsigned)cT) continue;
#pragma unroll
    for (int rr = 0; rr < 4; ++rr) {   // input rows h0-1 .. h0+2
      int hh = h0 + rr - 1;
      if ((unsigned)hh >= (unsigned)cH) continue;
      size_t rb = ((size_t)b * cL + (tt << 10) + (hh << 5)) * cC + c;
      float4 xm1 = (w0 > 0)  ? ld4<F32>(xin, rb + (size_t)(w0 - 1) * cC) : zero;
      float4 x0v = ld4<F32>(xin, rb + (size_t)w0 * cC);
      float4 x1v = ld4<F32>(xin, rb + (size_t)(w0 + 1) * cC);
      float4 x2v = (w0 < 30) ? ld4<F32>(xin, rb + (size_t)(w0 + 2) * cC) : zero;
      if (rr < 3) {                      // output h0, dy = rr
        const float* wr = wT + (dz * 9 + rr * 3) * cC + c;
        float4 wv0 = *(const float4*)(wr);
        float4 wv1 = *(const float4*)(wr + cC);
        float4 wv2 = *(const float4*)(wr + 2 * cC);
        a00 = cfma(cfma(cfma(a00, wv0, xm1), wv1, x0v), wv2, x1v);
        a01 = cfma(cfma(cfma(a01, wv0, x0v), wv1, x1v), wv2, x2v);
      }
      if (rr >= 1) {                     // output h0+1, dy = rr-1
        const float* wr = wT + (dz * 9 + (rr - 1) * 3) * cC + c;
        float4 wv0 = *(const float4*)(wr);
        float4 wv1 = *(const float4*)(wr + cC);
        float4 wv2 = *(const float4*)(wr + 2 * cC);
        a10 = cfma(cfma(cfma(a10, wv0, xm1), wv1, x0v), wv2, x1v);
        a11 = cfma(cfma(cfma(a11, wv0, x0v), wv1, x1v), wv2, x2v);
      }
    }
  }
  size_t v00 = (size_t)b * cL + (t << 10) + (h0 << 5) + w0;
#pragma unroll
  for (int oh = 0; oh < 2; ++oh) {
#pragma unroll
    for (int ow = 0; ow < 2; ++ow) {
      size_t bv = v00 + (size_t)(oh << 5) + ow;
      float4 acc = (oh == 0) ? (ow == 0 ? a00 : a01) : (ow == 0 ? a10 : a11);
      float4 r0 = ld4<F32>(xin, bv * cC + c);
      *(float4*)(out + bv * cC + c) =
          make_float4(r0.x + acc.x, r0.y + acc.y, r0.z + acc.z, r0.w + acc.w);
    }
  }
}

__global__ void __launch_bounds__(256) cpe_kernel(
    const void* __restrict__ xin, const float* __restrict__ wT,
    const float* __restrict__ bs, const int* __restrict__ flg, int afidx,
    float* __restrict__ out) {
  int idx = blockIdx.x * 256 + threadIdx.x;
  if (idx >= cBL * cC / 16) return;
  if (flg[afidx]) cpe_body<1>(xin, wT, bs, idx, out);
  else            cpe_body<0>(xin, wT, bs, idx, out);
}

// ---------- depthwise conv on DI + SiLU: bf16 in/out, 2x2 voxels/thread ----------
__global__ void __launch_bounds__(256) dwconv_silu_kernel(
    const unsigned short* __restrict__ xin, const float* __restrict__ wT,
    const float* __restrict__ bs, unsigned short* __restrict__ out) {
  int idx = blockIdx.x * 256 + threadIdx.x;
  if (idx >= cBL * cDI / 16) return;
  int d = (idx % (cDI / 4)) * 4;
  int rest = idx / (cDI / 4);
  int w0 = (rest & 15) << 1; rest >>= 4;
  int h0 = (rest & 15) << 1; rest >>= 4;
  int t = rest & 7; int b = rest >> 3;
  float4 bias = *(const float4*)(bs + d);
  float4 a00 = bias, a01 = bias, a10 = bias, a11 = bias;
  const float4 zero = make_float4(0.f, 0.f, 0.f, 0.f);
#pragma unroll
  for (int dz = 0; dz < 3; ++dz) {
    int tt = t + dz - 1; if ((unsigned)tt >= (unsigned)cT) continue;
#pragma unroll
    for (int rr = 0; rr < 4; ++rr) {
      int hh = h0 + rr - 1;
      if ((unsigned)hh >= (unsigned)cH) continue;
      size_t rb = ((size_t)b * cL + (tt << 10) + (hh << 5)) * cDI + d;
      float4 xm1 = (w0 > 0)  ? ld4<0>(xin, rb + (size_t)(w0 - 1) * cDI) : zero;
      float4 x0v = ld4<0>(xin, rb + (size_t)w0 * cDI);
      float4 x1v = ld4<0>(xin, rb + (size_t)(w0 + 1) * cDI);
      float4 x2v = (w0 < 30) ? ld4<0>(xin, rb + (size_t)(w0 + 2) * cDI) : zero;
      if (rr < 3) {
        const float* wr = wT + (dz * 9 + rr * 3) * cDI + d;
        float4 wv0 = *(const float4*)(wr);
        float4 wv1 = *(const float4*)(wr + cDI);
        float4 wv2 = *(const float4*)(wr + 2 * cDI);
        a00 = cfma(cfma(cfma(a00, wv0, xm1), wv1, x0v), wv2, x1v);
        a01 = cfma(cfma(cfma(a01, wv0, x0v), wv1, x1v), wv2, x2v);
      }
      if (rr >= 1) {
        const float* wr = wT + (dz * 9 + (rr - 1) * 3) * cDI + d;
        float4 wv0 = *(const float4*)(wr);
        float4 wv1 = *(const float4*)(wr + cDI);
        float4 wv2 = *(const float4*)(wr + 2 * cDI);
        a10 = cfma(cfma(cfma(a10, wv0, xm1), wv1, x0v), wv2, x1v);
        a11 = cfma(cfma(cfma(a11, wv0, x0v), wv1, x1v), wv2, x2v);
      }
    }
  }
  size_t v00 = (size_t)b * cL + (t << 10) + (h0 << 5) + w0;
#pragma unroll
  for (int oh = 0; oh < 2; ++oh) {
#pragma unroll
    for (int ow = 0; ow < 2; ++ow) {
      size_t bv = v00 + (size_t)(oh << 5) + ow;
      float4 acc = (oh == 0) ? (ow == 0 ? a00 : a01) : (ow == 0 ? a10 : a11);
      ushort4 o;
      o.x = (unsigned short)f2bf(siluf(acc.x));
      o.y = (unsigned short)f2bf(siluf(acc.y));
      o.z = (unsigned short)f2bf(siluf(acc.z));
      o.w = (unsigned short)f2bf(siluf(acc.w));
      *(ushort4*)(out + bv * cDI + d) = o;
    }
  }
}

// ---------- wave-per-row LayerNorm (C=192): no LDS, no barriers, bf16 out ----------
__global__ void __launch_bounds__(256) lnb_kernel(
    const float* __restrict__ in, const void* __restrict__ g,
    const void* __restrict__ bb, const int* __restrict__ flg,
    unsigned short* __restrict__ out) {
  int pf = flg[1];
  int row = blockIdx.x * 4 + (threadIdx.x >> 6);
  int lane = threadIdx.x & 63;
  const float* x = in + (size_t)row * cC;
  float v0 = x[lane], v1 = x[lane + 64], v2 = x[lane + 128];
  float s1 = v0 + v1 + v2;
  float s2 = v0 * v0 + v1 * v1 + v2 * v2;
#pragma unroll
  for (int off = 32; off > 0; off >>= 1) {
    s1 += __shfl_xor(s1, off);
    s2 += __shfl_xor(s2, off);
  }
  float mean = s1 * (1.f / cC);
  float var = s2 * (1.f / cC) - mean * mean;
  float rstd = rsqrtf(var + 1e-6f);
  unsigned short* o = out + (size_t)row * cC;
  o[lane]       = (unsigned short)f2bf((v0 - mean) * rstd * ldsel(g, lane, pf)       + ldsel(bb, lane, pf));
  o[lane + 64]  = (unsigned short)f2bf((v1 - mean) * rstd * ldsel(g, lane + 64, pf)  + ldsel(bb, lane + 64, pf));
  o[lane + 128] = (unsigned short)f2bf((v2 - mean) * rstd * ldsel(g, lane + 128, pf) + ldsel(bb, lane + 128, pf));
}

// ---------- text conditioning ----------
__global__ void __launch_bounds__(384) text_cond_kernel(
    const void* __restrict__ text, const void* __restrict__ tw,
    const void* __restrict__ tb, const int* __restrict__ flg,
    float* __restrict__ cond) {
  int af = flg[0], pf = flg[1];
  __shared__ float mean[cC];
  int b = blockIdx.x;
  for (int c = threadIdx.x; c < cC; c += 384) {
    float s = 0.f;
    for (int t = 0; t < cLT; ++t) s += ldsel(text, ((size_t)b * cLT + t) * cC + c, af);
    mean[c] = s * (1.f / cLT);
  }
  __syncthreads();
  int di = threadIdx.x;
  float a = ldsel(tb, di, pf);
  for (int c = 0; c < cC; ++c) a += mean[c] * ldsel(tw, di * cC + c, pf);
  cond[b * cDI + di] = siluf(a);
}

// ---------- MFMA GEMM: out = epilogue(A[M,K]bf16 @ W[N,K]^T), bf16 compute ----------
template <int MODE, int BN>
__global__ void __launch_bounds__(256) gemm_mfma_kernel(
    const void* __restrict__ A, const void* __restrict__ W,
    int N, int K, const void* __restrict__ bias, const int* __restrict__ flg,
    const float* __restrict__ extra, float* __restrict__ out,
    unsigned short* __restrict__ out2) {
  constexpr int BM = 128, BK = 64, PK = 72;
  constexpr int NI = BN / 32;           // n-fragments per wave
  __shared__ short As[BM * PK];
  __shared__ short Bs[BN * PK];
  int pf = flg[1];
  int tid = threadIdx.x;
  int m0 = blockIdx.y * BM, n0 = blockIdx.x * BN;
  int lane = tid & 63, wv = tid >> 6;
  int wm = (wv >> 1) * 64, wn = (wv & 1) * (BN / 2);
  int lr = lane & 15, quad = lane >> 4;
  f32x4 acc[4][NI];
#pragma unroll
  for (int mi = 0; mi < 4; ++mi)
#pragma unroll
    for (int ni = 0; ni < NI; ++ni) { acc[mi][ni][0]=0.f; acc[mi][ni][1]=0.f; acc[mi][ni][2]=0.f; acc[mi][ni][3]=0.f; }
  int ar = tid >> 1, aks = (tid & 1) * 32;   // 128 rows x 2 thr, 32 elems each
  int wr, wks;
  if (BN == 64) { wr = tid >> 2; wks = (tid & 3) * 16; }
  else          { wr = tid >> 1; wks = (tid & 1) * 32; }
  constexpr int BEL = (BN == 64) ? 16 : 32;  // B elems per thread
  for (int k0 = 0; k0 < K; k0 += BK) {
    {
      const unsigned short* ap = (const unsigned short*)A + (size_t)(m0 + ar) * K + k0 + aks;
      short* da = &As[ar * PK + aks];
#pragma unroll
      for (int i = 0; i < 4; ++i)
        *(bf16x8*)(da + i * 8) = *(const bf16x8*)(ap + i * 8);
    }
    {
      int nr = n0 + wr;
      short* db = &Bs[wr * PK + wks];
      if (nr < N) {
        size_t wi = (size_t)nr * K + k0 + wks;
        if (pf) {
#pragma unroll
          for (int i = 0; i < BEL / 4; ++i) {
            float4 wvv = *(const float4*)((const float*)W + wi + i * 4);
            short4v h;
            h.x = f2bf(wvv.x); h.y = f2bf(wvv.y); h.z = f2bf(wvv.z); h.w = f2bf(wvv.w);
            *(short4v*)(db + i * 4) = h;
          }
        } else {
#pragma unroll
          for (int i = 0; i < BEL / 8; ++i)
            *(bf16x8*)(db + i * 8) = *(const bf16x8*)((const unsigned short*)W + wi + i * 8);
        }
      } else {
        short4v z; z.x = 0; z.y = 0; z.z = 0; z.w = 0;
#pragma unroll
        for (int i = 0; i < BEL / 4; ++i)
          *(short4v*)(db + i * 4) = z;
      }
    }
    __syncthreads();
    bf16x8 af[2][4], bfr[2][NI];
#pragma unroll
    for (int kk = 0; kk < 2; ++kk) {
#pragma unroll
      for (int mi = 0; mi < 4; ++mi)
        af[kk][mi] = *(const bf16x8*)&As[(wm + mi * 16 + lr) * PK + kk * 32 + quad * 8];
#pragma unroll
      for (int ni = 0; ni < NI; ++ni)
        bfr[kk][ni] = *(const bf16x8*)&Bs[(wn + ni * 16 + lr) * PK + kk * 32 + quad * 8];
    }
#pragma unroll
    for (int kk = 0; kk < 2; ++kk)
#pragma unroll
      for (int mi = 0; mi < 4; ++mi)
#pragma unroll
        for (int ni = 0; ni < NI; ++ni)
          acc[mi][ni] = __builtin_amdgcn_mfma_f32_16x16x32_bf16(af[kk][mi], bfr[kk][ni], acc[mi][ni], 0, 0, 0);
    __syncthreads();
  }
#pragma unroll
  for (int mi = 0; mi < 4; ++mi) {
#pragma unroll
    for (int ni = 0; ni < NI; ++ni) {
#pragma unroll
      for (int r = 0; r < 4; ++r) {
        int m = m0 + wm + mi * 16 + quad * 4 + r;
        int n = n0 + wn + ni * 16 + lr;
        float v = acc[mi][ni][r];
        if (MODE == 0) {
          float bvv = ldsel(bias, n, pf);
          int b = m >> 13;
          if (n < cDI)
            ((unsigned short*)out)[(size_t)m * cDI + n] =
                (unsigned short)f2bf(v + bvv + extra[b * cDI + n]);
          else
            out2[(size_t)m * cDI + (n - cDI)] = (unsigned short)f2bf(v + bvv);
        } else if (MODE == 1) {
          if (n < cK * XROW) {
            int k = n / XROW, c = n - k * XROW;
            int b = m >> 13, vv = m & (cL - 1);
            int t = vv >> 10, q = vv & 1023, h = q >> 5, w = q & 31;
            int l1 = (t << 10) + (w << 5) + h;
            int lk = (k == 0) ? vv : (k == 1) ? l1 : (k == 2) ? (cL - 1 - vv) : (cL - 1 - l1);
            out[((size_t)(b * cK + k) * cL + lk) * XSTR + c] = v;
          }
        } else if (MODE == 2) {
          out[(size_t)m * cC + n] = v + extra[(size_t)m * cC + n];
        } else if (MODE == 3) {
          ((unsigned short*)out)[(size_t)m * cHID + n] =
              (unsigned short)f2bf(gelut(v + ldsel(bias, n, pf)));
        } else {
          out[(size_t)m * cC + n] = v + ldsel(bias, n, pf) + extra[(size_t)m * cC + n];
        }
      }
    }
  }
}

// voxel index for scan position l in direction k
DEV int scan_voxel(int k, int l) {
  if (k == 0) return l;
  if (k == 2) return cL - 1 - l;
  int ll = (k == 1) ? l : (cL - 1 - l);
  int t = ll >> 10, q = ll & 1023, w = q >> 5, h = q & 31;
  return (t << 10) + (h << 5) + w;
}

// packed dtr dot from raw LDS row pointer
DEV float dtdot_rp(const float4* rp, const f32x2 (&wp)[6], float dtb) {
  float4 q0 = rp[0], q1 = rp[1], q2 = rp[2];
  f32x2 acc = mk2(dtb, 0.f);
  acc += mk2(q0.x, q0.y) * wp[0];
  acc += mk2(q0.z, q0.w) * wp[1];
  acc += mk2(q1.x, q1.y) * wp[2];
  acc += mk2(q1.z, q1.w) * wp[3];
  acc += mk2(q2.x, q2.y) * wp[4];
  acc += mk2(q2.z, q2.w) * wp[5];
  return acc[0] + acc[1];
}

// log-depth power tree: pw[i] = (a^(2i+1), a^(2i+2)), depth 4
DEV void powtree(float a1, f32x2 (&pw)[8]) {
  float a2 = a1 * a1;
  f32x2 sq  = mk2(a2, a2);
  f32x2 sq2 = sq * sq;      // (a4,a4)
  f32x2 sq4 = sq2 * sq2;    // (a8,a8)
  pw[0] = mk2(a1, a2);
  pw[1] = pw[0] * sq;
  pw[2] = pw[0] * sq2;
  pw[3] = pw[1] * sq2;
  pw[4] = pw[0] * sq4;
  pw[5] = pw[1] * sq4;
  pw[6] = pw[2] * sq4;
  pw[7] = pw[3] * sq4;
}

// ---------- scan pass 1 ----------
// Batched-transcendental fast path: per 8 steps, phase A computes the 8
// independent {dtr-dot -> softplus -> exp2} chains (ILP-8, u-gathers issued
// ahead and hidden under it); phase B runs the recurrence whose dependent
// path is now only {depth-4 power tree + 1 packed FMA per h-pair}.
__global__ void __launch_bounds__(128, 3) scan1_kernel(
    const unsigned short* __restrict__ xch, const float* __restrict__ xdbl,
    const void* __restrict__ dtw, const void* __restrict__ dtbv,
    const void* __restrict__ alog, const void* __restrict__ dsv,
    const int* __restrict__ flg,
    unsigned short* __restrict__ ys0, unsigned short* __restrict__ ys1,
    unsigned short* __restrict__ ys2, unsigned short* __restrict__ ys3,
    unsigned short* __restrict__ hend, unsigned short* __restrict__ pend) {
  __shared__ float rows[SEGLEN * XSTR];   // 64 x 48 floats = 12 KB
  int pf = flg[1];
  int tid = threadIdx.x;
  int d = blockIdx.x * 128 + tid;
  int bks = blockIdx.y;
  int s = bks & (SEG - 1); int bk = bks / SEG; int k = bk & 3; int b = bk >> 2;
  int l0 = s * SEGLEN;
  {
    const float4* src = (const float4*)(xdbl + ((size_t)bk * cL + l0) * XSTR);
    float4* dst = (float4*)rows;
#pragma unroll
    for (int i = 0; i < (SEGLEN * XSTR / 4) / 128; ++i)   // 6 iters
      dst[tid + i * 128] = src[tid + i * 128];
  }
  float wdt[cDTR];
#pragma unroll
  for (int r = 0; r < cDTR; ++r) wdt[r] = ldsel(dtw, (size_t)(k * cDI + d) * cDTR + r, pf);
  f32x2 wp[6];
#pragma unroll
  for (int r = 0; r < 6; ++r) wp[r] = mk2(wdt[2 * r], wdt[2 * r + 1]);
  float dtb = ldsel(dtbv, k * cDI + d, pf);
  float ac[cN];
#pragma unroll
  for (int n = 0; n < cN; ++n)
    ac[n] = -__expf(ldsel(alog, (size_t)(k * cDI + d) * cN + n, pf)) * 1.4426950408889634f;
  bool fast = true;
#pragma unroll
  for (int n = 1; n < cN; ++n)
    fast = fast && (fabsf(ac[n] - (float)(n + 1) * ac[0]) <= 1e-3f * fabsf(ac[n]));
  float Dsd = ldsel(dsv, k * cDI + d, pf);
  size_t so = ((size_t)bks * cDI + d) * cN;
  const unsigned short* xcb = xch + (size_t)b * cL * cDI + d;
  unsigned short* ysk = (k == 0) ? ys0 : (k == 1) ? ys1 : (k == 2) ? ys2 : ys3;
  unsigned short* ysrow = ysk + ((size_t)b * cL + l0) * cDI + d;
  __syncthreads();
  if (fast) {
    float ac0 = ac[0];
    float P1 = 1.f;
    f32x2 h2[8];
#pragma unroll
    for (int i = 0; i < 8; ++i) h2[i] = mk2(0.f, 0.f);
    for (int st0 = 0; st0 < SEGLEN; st0 += 8) {
      float uu[8];
#pragma unroll
      for (int i = 0; i < 8; ++i)
        uu[i] = bfu2f(xcb[(size_t)scan_voxel(k, l0 + st0 + i) * cDI]);
      float a18[8], dtu8[8];
#pragma unroll
      for (int i = 0; i < 8; ++i) {
        const float4* rp = (const float4*)(rows + (st0 + i) * XSTR);
        float dt = softplusf(dtdot_rp(rp, wp, dtb));
        a18[i] = exp2f(dt * ac0);
        dtu8[i] = dt * uu[i];
      }
#pragma unroll
      for (int i = 0; i < 8; ++i) {
        const float4* rp = (const float4*)(rows + (st0 + i) * XSTR);
        f32x2 pw[8];
        powtree(a18[i], pw);
        float4 b0 = rp[3], b1 = rp[4], b2 = rp[5], b3 = rp[6];
        float4 c0 = rp[7], c1 = rp[8], c2 = rp[9], c3 = rp[10];
        f32x2 dtu2 = mk2(dtu8[i], dtu8[i]);
        f32x2 y0 = mk2(Dsd * uu[i], 0.f);
        f32x2 y1 = mk2(0.f, 0.f), y2 = mk2(0.f, 0.f), y3 = mk2(0.f, 0.f);
        h2[0] = h2[0]*pw[0] + dtu2*mk2(b0.x,b0.y); y0 += h2[0]*mk2(c0.x,c0.y);
        h2[1] = h2[1]*pw[1] + dtu2*mk2(b0.z,b0.w); y1 += h2[1]*mk2(c0.z,c0.w);
        h2[2] = h2[2]*pw[2] + dtu2*mk2(b1.x,b1.y); y2 += h2[2]*mk2(c1.x,c1.y);
        h2[3] = h2[3]*pw[3] + dtu2*mk2(b1.z,b1.w); y3 += h2[3]*mk2(c1.z,c1.w);
        h2[4] = h2[4]*pw[4] + dtu2*mk2(b2.x,b2.y); y0 += h2[4]*mk2(c2.x,c2.y);
        h2[5] = h2[5]*pw[5] + dtu2*mk2(b2.z,b2.w); y1 += h2[5]*mk2(c2.z,c2.w);
        h2[6] = h2[6]*pw[6] + dtu2*mk2(b3.x,b3.y); y2 += h2[6]*mk2(c3.x,c3.y);
        h2[7] = h2[7]*pw[7] + dtu2*mk2(b3.z,b3.w); y3 += h2[7]*mk2(c3.z,c3.w);
        P1 *= a18[i];
        f32x2 tt = (y0 + y1) + (y2 + y3);
        ysrow[(size_t)(st0 + i) * cDI] = (unsigned short)f2bf(tt[0] + tt[1]);
      }
    }
    float pp = P1;
#pragma unroll
    for (int i = 0; i < 8; ++i) {
      hend[so + 2*i]     = (unsigned short)f2bf(h2[i][0]);
      hend[so + 2*i + 1] = (unsigned short)f2bf(h2[i][1]);
    }
#pragma unroll
    for (int n = 0; n < cN; ++n) {
      pend[so + n] = (unsigned short)f2bf(pp);
      pp *= P1;
    }
  } else {
    float h[cN], P[cN];
#pragma unroll
    for (int n = 0; n < cN; ++n) { h[n] = 0.f; P[n] = 1.f; }
    for (int st = 0; st < SEGLEN; ++st) {
      int l = l0 + st;
      const float4* rp = (const float4*)(rows + st * XSTR);
      float4 q0 = rp[0], q1 = rp[1], q2 = rp[2];
      float s0 = dtb + q0.x*wdt[0] + q0.z*wdt[2] + q1.x*wdt[4] + q1.z*wdt[6] + q2.x*wdt[8] + q2.z*wdt[10];
      float s1 = q0.y*wdt[1] + q0.w*wdt[3] + q1.y*wdt[5] + q1.w*wdt[7] + q2.y*wdt[9] + q2.w*wdt[11];
      float dt = softplusf(s0 + s1);
      float Bv[cN], Cv[cN];
      float4 qb0 = rp[3], qb1 = rp[4], qb2 = rp[5], qb3 = rp[6];
      float4 qc0 = rp[7], qc1 = rp[8], qc2 = rp[9], qc3 = rp[10];
      Bv[0]=qb0.x; Bv[1]=qb0.y; Bv[2]=qb0.z; Bv[3]=qb0.w;
      Bv[4]=qb1.x; Bv[5]=qb1.y; Bv[6]=qb1.z; Bv[7]=qb1.w;
      Bv[8]=qb2.x; Bv[9]=qb2.y; Bv[10]=qb2.z; Bv[11]=qb2.w;
      Bv[12]=qb3.x; Bv[13]=qb3.y; Bv[14]=qb3.z; Bv[15]=qb3.w;
      Cv[0]=qc0.x; Cv[1]=qc0.y; Cv[2]=qc0.z; Cv[3]=qc0.w;
      Cv[4]=qc1.x; Cv[5]=qc1.y; Cv[6]=qc1.z; Cv[7]=qc1.w;
      Cv[8]=qc2.x; Cv[9]=qc2.y; Cv[10]=qc2.z; Cv[11]=qc2.w;
      Cv[12]=qc3.x; Cv[13]=qc3.y; Cv[14]=qc3.z; Cv[15]=qc3.w;
      int v = scan_voxel(k, l);
      float u = bfu2f(xcb[(size_t)v * cDI]);
      float dtu = dt * u;
      float y = Dsd * u;
#pragma unroll
      for (int n = 0; n < cN; ++n) {
        float a = exp2f(dt * ac[n]);
        h[n] = h[n] * a + dtu * Bv[n];
        P[n] *= a;
        y += h[n] * Cv[n];
      }
      ysrow[(size_t)st * cDI] = (unsigned short)f2bf(y);
    }
#pragma unroll
    for (int n = 0; n < cN; ++n) {
      hend[so + n] = (unsigned short)f2bf(h[n]);
      pend[so + n] = (unsigned short)f2bf(P[n]);
    }
  }
}

// ---------- scan pass 2 (serial prefix over segments; fp32 recurrence, bf16 storage) ----------
__global__ void __launch_bounds__(256) scan2_kernel(
    unsigned short* __restrict__ hend, const unsigned short* __restrict__ pend) {
  int tid = blockIdx.x * 256 + threadIdx.x;
  int bk = tid / (cDI * cN); int r = tid - bk * (cDI * cN);
  float g = 0.f;
  for (int s = 0; s < SEG; ++s) {
    size_t o = ((size_t)(bk * SEG + s) * cDI * cN) + r;
    float he = bfu2f(hend[o]), pe = bfu2f(pend[o]);
    hend[o] = (unsigned short)f2bf(g);
    g = pe * g + he;
  }
}

// ---------- scan pass 3 (owned read-add-store; batched transcendentals) ----------
__global__ void __launch_bounds__(128, 3) scan3_kernel(
    const float* __restrict__ xdbl,
    const void* __restrict__ dtw, const void* __restrict__ dtbv,
    const void* __restrict__ alog, const int* __restrict__ flg,
    const unsigned short* __restrict__ hin,
    unsigned short* __restrict__ ys0, unsigned short* __restrict__ ys1,
    unsigned short* __restrict__ ys2, unsigned short* __restrict__ ys3) {
  int bks = blockIdx.y;
  int s = bks & (SEG - 1);
  if (s == 0) return;
  __shared__ float rows[SEGLEN * XSTR];
  int pf = flg[1];
  int tid = threadIdx.x;
  int d = blockIdx.x * 128 + tid;
  int bk = bks / SEG; int k = bk & 3; int b = bk >> 2;
  int l0 = s * SEGLEN;
  {
    const float4* src = (const float4*)(xdbl + ((size_t)bk * cL + l0) * XSTR);
    float4* dst = (float4*)rows;
#pragma unroll
    for (int i = 0; i < (SEGLEN * XSTR / 4) / 128; ++i)
      dst[tid + i * 128] = src[tid + i * 128];
  }
  float wdt[cDTR];
#pragma unroll
  for (int r = 0; r < cDTR; ++r) wdt[r] = ldsel(dtw, (size_t)(k * cDI + d) * cDTR + r, pf);
  f32x2 wp[6];
#pragma unroll
  for (int r = 0; r < 6; ++r) wp[r] = mk2(wdt[2 * r], wdt[2 * r + 1]);
  float dtb = ldsel(dtbv, k * cDI + d, pf);
  float ac[cN];
#pragma unroll
  for (int n = 0; n < cN; ++n)
    ac[n] = -__expf(ldsel(alog, (size_t)(k * cDI + d) * cN + n, pf)) * 1.4426950408889634f;
  bool fast = true;
#pragma unroll
  for (int n = 1; n < cN; ++n)
    fast = fast && (fabsf(ac[n] - (float)(n + 1) * ac[0]) <= 1e-3f * fabsf(ac[n]));
  size_t so = ((size_t)bks * cDI + d) * cN;
  unsigned short* ysk = (k == 0) ? ys0 : (k == 1) ? ys1 : (k == 2) ? ys2 : ys3;
  unsigned short* ysrow = ysk + ((size_t)b * cL + l0) * cDI + d;
  __syncthreads();
  if (fast) {
    float ac0 = ac[0];
    f32x2 g2[8];
#pragma unroll
    for (int i = 0; i < 8; ++i)
      g2[i] = mk2(bfu2f(hin[so + 2*i]), bfu2f(hin[so + 2*i + 1]));
    for (int st0 = 0; st0 < SEGLEN; st0 += 8) {
      float a18[8];
#pragma unroll
      for (int i = 0; i < 8; ++i) {
        const float4* rp = (const float4*)(rows + (st0 + i) * XSTR);
        float dt = softplusf(dtdot_rp(rp, wp, dtb));
        a18[i] = exp2f(dt * ac0);
      }
#pragma unroll
      for (int i = 0; i < 8; ++i) {
        const float4* rp = (const float4*)(rows + (st0 + i) * XSTR);
        f32x2 pw[8];
        powtree(a18[i], pw);
        float4 c0 = rp[7], c1 = rp[8], c2 = rp[9], c3 = rp[10];
        f32x2 y0 = mk2(0.f, 0.f), y1 = mk2(0.f, 0.f), y2 = mk2(0.f, 0.f), y3 = mk2(0.f, 0.f);
        g2[0] *= pw[0]; y0 += g2[0]*mk2(c0.x,c0.y);
        g2[1] *= pw[1]; y1 += g2[1]*mk2(c0.z,c0.w);
        g2[2] *= pw[2]; y2 += g2[2]*mk2(c1.x,c1.y);
        g2[3] *= pw[3]; y3 += g2[3]*mk2(c1.z,c1.w);
        g2[4] *= pw[4]; y0 += g2[4]*mk2(c2.x,c2.y);
        g2[5] *= pw[5]; y1 += g2[5]*mk2(c2.z,c2.w);
        g2[6] *= pw[6]; y2 += g2[6]*mk2(c3.x,c3.y);
        g2[7] *= pw[7]; y3 += g2[7]*mk2(c3.z,c3.w);
        f32x2 tt = (y0 + y1) + (y2 + y3);
        size_t ii = (size_t)(st0 + i) * cDI;
        ysrow[ii] = (unsigned short)f2bf(bfu2f(ysrow[ii]) + tt[0] + tt[1]);
      }
    }
  } else {
    float g[cN];
#pragma unroll
    for (int n = 0; n < cN; ++n) g[n] = bfu2f(hin[so + n]);
    for (int st = 0; st < SEGLEN; ++st) {
      const float4* rp = (const float4*)(rows + st * XSTR);
      float4 q0 = rp[0], q1 = rp[1], q2 = rp[2];
      float s0 = dtb + q0.x*wdt[0] + q0.z*wdt[2] + q1.x*wdt[4] + q1.z*wdt[6] + q2.x*wdt[8] + q2.z*wdt[10];
      float s1 = q0.y*wdt[1] + q0.w*wdt[3] + q1.y*wdt[5] + q1.w*wdt[7] + q2.y*wdt[9] + q2.w*wdt[11];
      float dt = softplusf(s0 + s1);
      float Cv[cN];
      float4 qc0 = rp[7], qc1 = rp[8], qc2 = rp[9], qc3 = rp[10];
      Cv[0]=qc0.x; Cv[1]=qc0.y; Cv[2]=qc0.z; Cv[3]=qc0.w;
      Cv[4]=qc1.x; Cv[5]=qc1.y; Cv[6]=qc1.z; Cv[7]=qc1.w;
      Cv[8]=qc2.x; Cv[9]=qc2.y; Cv[10]=qc2.z; Cv[11]=qc2.w;
      Cv[12]=qc3.x; Cv[13]=qc3.y; Cv[14]=qc3.z; Cv[15]=qc3.w;
      float y = 0.f;
#pragma unroll
      for (int n = 0; n < cN; ++n) {
        float a = exp2f(dt * ac[n]);
        g[n] *= a;
        y += g[n] * Cv[n];
      }
      size_t ii = (size_t)st * cDI;
      ysrow[ii] = (unsigned short)f2bf(bfu2f(ysrow[ii]) + y);
    }
  }
}

// ---------- merge: wave-per-row gather of 4 dirs + out_norm LN + silu(z) gate ----------
__global__ void __launch_bounds__(256) merge_kernel(
    const unsigned short* __restrict__ ys0, const unsigned short* __restrict__ ys1,
    const unsigned short* __restrict__ ys2, const unsigned short* __restrict__ ys3,
    const unsigned short* __restrict__ zh,
    const void* __restrict__ ong, const void* __restrict__ onb,
    const int* __restrict__ flg, unsigned short* __restrict__ yg) {
  int pf = flg[1];
  int bv = blockIdx.x * 4 + (threadIdx.x >> 6);
  int lane = threadIdx.x & 63;
  int v = bv & (cL - 1); int b = bv >> 13;
  int t = v >> 10, q = v & 1023, hh = q >> 5, ww = q & 31;
  int l1 = (t << 10) + (ww << 5) + hh;
  size_t r0 = ((size_t)b * cL + v) * cDI;
  size_t r1 = ((size_t)b * cL + l1) * cDI;
  size_t r2 = ((size_t)b * cL + (cL - 1 - v)) * cDI;
  size_t r3 = ((size_t)b * cL + (cL - 1 - l1)) * cDI;
  float vals[6]; float s1 = 0.f, s2 = 0.f;
#pragma unroll
  for (int i = 0; i < 6; ++i) {
    int d = lane + i * 64;
    float x = bfu2f(ys0[r0 + d]) + bfu2f(ys1[r1 + d]) +
              bfu2f(ys2[r2 + d]) + bfu2f(ys3[r3 + d]);
    vals[i] = x; s1 += x; s2 += x * x;
  }
#pragma unroll
  for (int off = 32; off > 0; off >>= 1) {
    s1 += __shfl_xor(s1, off);
    s2 += __shfl_xor(s2, off);
  }
  float mean = s1 * (1.f / cDI);
  float var = s2 * (1.f / cDI) - mean * mean;
  float rstd = rsqrtf(var + 1e-6f);
  const unsigned short* zr = zh + (size_t)bv * cDI;
  unsigned short* og = yg + (size_t)bv * cDI;
#pragma unroll
  for (int i = 0; i < 6; ++i) {
    int d = lane + i * 64;
    float xn = (vals[i] - mean) * rstd * ldsel(ong, d, pf) + ldsel(onb, d, pf);
    og[d] = (unsigned short)f2bf(xn * siluf(bfu2f(zr[d])));
  }
}

}  // namespace

extern "C" void kernel_launch(void* const* d_in, const int* in_sizes, int n_in,
                              void* d_out, int out_size, void* d_ws, size_t ws_size,
                              hipStream_t stream) {
  (void)in_sizes; (void)n_in; (void)out_size; (void)ws_size;
  const void* x    = d_in[0];
  const void* text = d_in[1];
  const void* c1w  = d_in[2];
  const void* c1b  = d_in[3];
  const void* c2w  = d_in[4];
  const void* c2b  = d_in[5];
  const void* n1g  = d_in[6];
  const void* n1b  = d_in[7];
  const void* n2g  = d_in[8];
  const void* n2b  = d_in[9];
  const void* ipw  = d_in[10];
  const void* ipb  = d_in[11];
  const void* tpw  = d_in[12];
  const void* tpb  = d_in[13];
  const void* cvw  = d_in[14];
  const void* cvb  = d_in[15];
  const void* xpw  = d_in[16];
  const void* dtw  = d_in[17];
  const void* dtb  = d_in[18];
  const void* alog = d_in[19];
  const void* dsv  = d_in[20];
  const void* ong  = d_in[21];
  const void* onb  = d_in[22];
  const void* opw  = d_in[23];
  const void* f1w  = d_in[24];
  const void* f1b  = d_in[25];
  const void* f2w  = d_in[26];
  const void* f2b  = d_in[27];

  float* Wf = (float*)d_ws;

  // ---- slot arena (~125.9 MB), atomic-free scan + bf16 activations ----
  constexpr size_t oC  = 0;                              // 6,291,456
  constexpr size_t oD  = 6291456;                        // 3,145,728
  constexpr size_t oG  = 9437184;                        // 3,145,728
  constexpr size_t oA  = 12582912;                       // 6,291,456
  constexpr size_t oB  = 18874368;                       // 6,291,456
  constexpr size_t oE  = 25165824;                       // 3,145,728
  constexpr size_t oF  = 28311552;                       // 3,145,728
  constexpr size_t oCO = 31457280;                       // 768 (cond)
  constexpr size_t oFL = 31458048;                       // 4 ints (flags)
  constexpr size_t oWCV = 31458052;                      // 27*384
  constexpr size_t oBCV = 31468420;                      // 384
  constexpr size_t oW1  = 31468804;                      // 27*192
  constexpr size_t oB1  = 31473988;                      // 192
  constexpr size_t oW2  = 31474180;                      // 5184
  constexpr size_t oB2  = 31479364;                      // 192 -> end 31479556
  unsigned short* xch = (unsigned short*)(Wf + oC);            // bf16 silu(dwconv)
  unsigned short* ysd2 = (unsigned short*)(Wf + oC + 3145728); // ystream dir 2
  unsigned short* hbufh = (unsigned short*)(Wf + oC);          // fc1 out bf16
  float* xdbl = Wf + oD;
  unsigned short* ygh  = (unsigned short*)(Wf + oD);           // yg bf16 (after xdbl dead)
  unsigned short* xnh  = (unsigned short*)(Wf + oG);           // LN1 out bf16
  unsigned short* pendp = (unsigned short*)(Wf + oG);          // bf16, after xnh dead
  unsigned short* xib  = (unsigned short*)(Wf + oA);           // in_proj x-half bf16
  unsigned short* ysd0 = (unsigned short*)(Wf + oA);           // ystream dir 0 (xib dead)
  unsigned short* ysd1 = (unsigned short*)(Wf + oA + 3145728); // ystream dir 1
  float* x2   = Wf + oA;   // out_proj output (after ystream dead)
  unsigned short* zh   = (unsigned short*)(Wf + oB);           // z bf16
  unsigned short* ysd3 = (unsigned short*)(Wf + oB + 3145728); // ystream dir 3
  float* x3   = Wf + oB;
  float* x1   = Wf + oE;
  unsigned short* hendp = (unsigned short*)(Wf + oF);          // bf16
  unsigned short* xn2h = (unsigned short*)(Wf + oF);           // LN2 out bf16 (hend dead)
  float* cond = Wf + oCO;
  int*   flg  = (int*)(Wf + oFL);
  float* wcv = Wf + oWCV; float* bcv = Wf + oBCV;
  float* w1t = Wf + oW1;  float* b1t = Wf + oB1;
  float* w2t = Wf + oW2;  float* b2t = Wf + oB2;

  const int cpeBlocks = (cBL * cC / 16) / 256;    // 768 (2x2 voxels/thread)
  const int dwBlocks  = (cBL * cDI / 16) / 256;   // 1536 (2x2 voxels/thread)

  // 0. dtype detection + conv weight prep
  hipLaunchKernelGGL(detect_kernel, dim3(1), dim3(256), 0, stream,
                     (const unsigned short*)x, (const unsigned short*)ipw, flg);
  hipLaunchKernelGGL(prep_kernel, dim3(85), dim3(256), 0, stream,
                     cvw, cvb, c1w, c1b, c2w, c2b, flg, wcv, bcv, w1t, b1t, w2t, b2t);
  // 1. x1 = x + cpe1(x)
  hipLaunchKernelGGL(cpe_kernel, dim3(cpeBlocks), dim3(256), 0, stream,
                     x, w1t, b1t, flg, 0, x1);
  // 2. xnh = bf16(LN1(x1))  (wave-per-row, no barriers)
  hipLaunchKernelGGL(lnb_kernel, dim3(cBL / 4), dim3(256), 0, stream, x1, n1g, n1b, flg, xnh);
  // 3. cond
  hipLaunchKernelGGL(text_cond_kernel, dim3(cB), dim3(384), 0, stream, text, tpw, tpb, flg, cond);
  // 4. in_proj (MFMA BK=64, BN=128): xnh -> xib bf16 (+cond), zh bf16
  hipLaunchKernelGGL((gemm_mfma_kernel<0, 128>), dim3(2 * cDI / 128, cBL / 128), dim3(256), 0, stream,
                     xnh, ipw, 2 * cDI, cC, ipb, flg, cond, (float*)xib, zh);
  // 5. xch = bf16(silu(dwconv(xib)))
  hipLaunchKernelGGL(dwconv_silu_kernel, dim3(dwBlocks), dim3(256), 0, stream,
                     xib, wcv, bcv, xch);
  // 6. x_proj (MFMA BK=64, scatter to padded scan rows)
  hipLaunchKernelGGL((gemm_mfma_kernel<1, 64>), dim3((cK * XROW + 63) / 64, cBL / 128), dim3(256), 0, stream,
                     xch, xpw, cK * XROW, cDI, (const void*)nullptr, flg,
                     (const float*)nullptr, xdbl, (unsigned short*)nullptr);
  // 7-9. chunked selective scan (batched-transcendental fast paths)
  hipLaunchKernelGGL(scan1_kernel, dim3(cDI / 128, cB * cK * SEG), dim3(128), 0, stream,
                     xch, xdbl, dtw, dtb, alog, dsv, flg,
                     ysd0, ysd1, ysd2, ysd3, hendp, pendp);
  hipLaunchKernelGGL(scan2_kernel, dim3(cB * cK * cDI * cN / 256), dim3(256), 0, stream,
                     hendp, pendp);
  hipLaunchKernelGGL(scan3_kernel, dim3(cDI / 128, cB * cK * SEG), dim3(128), 0, stream,
                     xdbl, dtw, dtb, alog, flg, hendp, ysd0, ysd1, ysd2, ysd3);
  // 10. merge: wave-per-row gather + out_norm + gate -> yg bf16
  hipLaunchKernelGGL(merge_kernel, dim3(cBL / 4), dim3(256), 0, stream,
                     ysd0, ysd1, ysd2, ysd3, zh, ong, onb, flg, ygh);
  // 11. out_proj (MFMA BK=64) + residual(x1) -> x2 fp32
  hipLaunchKernelGGL((gemm_mfma_kernel<2, 64>), dim3(cC / 64, cBL / 128), dim3(256), 0, stream,
                     ygh, opw, cC, cDI, (const void*)nullptr, flg, x1, x2,
                     (unsigned short*)nullptr);
  // 12. x3 = x2 + cpe2(x2)  (flg[2]=1 -> fp32 input path)
  hipLaunchKernelGGL(cpe_kernel, dim3(cpeBlocks), dim3(256), 0, stream,
                     x2, w2t, b2t, flg, 2, x3);
  // 13. xn2h = bf16(LN2(x3))
  hipLaunchKernelGGL(lnb_kernel, dim3(cBL / 4), dim3(256), 0, stream, x3, n2g, n2b, flg, xn2h);
  // 14. fc1 + gelu -> hbufh bf16 (MFMA BK=64, BN=128)
  hipLaunchKernelGGL((gemm_mfma_kernel<3, 128>), dim3(cHID / 128, cBL / 128), dim3(256), 0, stream,
                     xn2h, f1w, cHID, cC, f1b, flg, (const float*)nullptr, (float*)hbufh,
                     (unsigned short*)nullptr);
  // 15. fc2 + bias + residual(x3) -> d_out fp32 (MFMA BK=64)
  hipLaunchKernelGGL((gemm_mfma_kernel<4, 64>), dim3(cC / 64, cBL / 128), dim3(256), 0, stream,
                     hbufh, f2w, cC, cHID, f2b, flg, x3, (float*)d_out,
                     (unsigned short*)nullptr);
}